// Round 1
// baseline (215.190 us; speedup 1.0000x reference)
//
#include <hip/hip_runtime.h>
#include <math.h>

#define COS_EPS 1e-8f

// One wave (64 lanes) per sample, grid-stride over samples.
// Each lane loads float4 chunks of the embedding row and the gathered
// prototype row; computes partial dot, |e|^2, |p|^2; butterfly-reduces
// across the 64-lane wave; lane 0 accumulates cos into a thread-local sum.
// Block-level LDS reduction -> one atomicAdd per block into d_ws[0].
__global__ __launch_bounds__(256) void assignment_loss_kernel(
    const float* __restrict__ emb,      // [B, D]
    const int*   __restrict__ labels,   // [B]
    const float* __restrict__ protos,   // [C, D]
    float*       __restrict__ acc,      // [1] accumulator (pre-zeroed)
    int B, int D)
{
    const int lane           = threadIdx.x & 63;
    const int wave_in_block  = threadIdx.x >> 6;
    const int waves_per_blk  = blockDim.x >> 6;
    const int global_wave    = blockIdx.x * waves_per_blk + wave_in_block;
    const int n_waves        = gridDim.x * waves_per_blk;
    const int nchunks        = D >> 8;   // 256 floats per chunk (64 lanes * float4)

    float local = 0.0f;

    for (int s = global_wave; s < B; s += n_waves) {
        const int lbl = labels[s];
        const float4* __restrict__ e =
            (const float4*)(emb + (size_t)s * (size_t)D);
        const float4* __restrict__ p =
            (const float4*)(protos + (size_t)lbl * (size_t)D);

        float dot = 0.0f, esq = 0.0f, psq = 0.0f;
        #pragma unroll
        for (int c = 0; c < 2; ++c) {           // D=512 -> 2 chunks (guarded below for generality)
            if (c < nchunks) {
                float4 ev = e[c * 64 + lane];
                float4 pv = p[c * 64 + lane];
                dot = fmaf(ev.x, pv.x, fmaf(ev.y, pv.y, fmaf(ev.z, pv.z, fmaf(ev.w, pv.w, dot))));
                esq = fmaf(ev.x, ev.x, fmaf(ev.y, ev.y, fmaf(ev.z, ev.z, fmaf(ev.w, ev.w, esq))));
                psq = fmaf(pv.x, pv.x, fmaf(pv.y, pv.y, fmaf(pv.z, pv.z, fmaf(pv.w, pv.w, psq))));
            }
        }
        // generic tail for D > 512 (not hit for this problem shape)
        for (int c = 2; c < nchunks; ++c) {
            float4 ev = e[c * 64 + lane];
            float4 pv = p[c * 64 + lane];
            dot = fmaf(ev.x, pv.x, fmaf(ev.y, pv.y, fmaf(ev.z, pv.z, fmaf(ev.w, pv.w, dot))));
            esq = fmaf(ev.x, ev.x, fmaf(ev.y, ev.y, fmaf(ev.z, ev.z, fmaf(ev.w, ev.w, esq))));
            psq = fmaf(pv.x, pv.x, fmaf(pv.y, pv.y, fmaf(pv.z, pv.z, fmaf(pv.w, pv.w, psq))));
        }

        // 64-lane butterfly reduction (wave = 64 on CDNA)
        #pragma unroll
        for (int off = 32; off > 0; off >>= 1) {
            dot += __shfl_xor(dot, off, 64);
            esq += __shfl_xor(esq, off, 64);
            psq += __shfl_xor(psq, off, 64);
        }

        if (lane == 0) {
            float en = fmaxf(sqrtf(esq), COS_EPS);   // torch F.cosine_similarity eps semantics
            float pn = fmaxf(sqrtf(psq), COS_EPS);
            local += dot / (en * pn);
        }
    }

    // block reduction: one partial per wave -> LDS -> one atomic per block
    __shared__ float smem[8];
    if (lane == 0) smem[wave_in_block] = local;
    __syncthreads();
    if (threadIdx.x == 0) {
        float bs = 0.0f;
        for (int w = 0; w < waves_per_blk; ++w) bs += smem[w];
        atomicAdd(acc, bs);
    }
}

__global__ void assignment_loss_finalize(const float* __restrict__ acc,
                                         float* __restrict__ out,
                                         float invB)
{
    out[0] = 1.0f - acc[0] * invB;
}

extern "C" void kernel_launch(void* const* d_in, const int* in_sizes, int n_in,
                              void* d_out, int out_size, void* d_ws, size_t ws_size,
                              hipStream_t stream) {
    const float* emb    = (const float*)d_in[0];   // [B, D] float32
    const int*   labels = (const int*)  d_in[1];   // [B] int
    const float* protos = (const float*)d_in[2];   // [C, D] float32
    float*       out    = (float*)d_out;           // scalar float32
    float*       acc    = (float*)d_ws;

    const int B = in_sizes[1];
    const int D = in_sizes[0] / B;                 // 512

    hipMemsetAsync(acc, 0, sizeof(float), stream); // d_ws is poisoned 0xAA each call

    const int block = 256;                         // 4 waves/block
    const int grid  = 1024;                        // 4 blocks/CU, 4096 waves total
    assignment_loss_kernel<<<grid, block, 0, stream>>>(emb, labels, protos, acc, B, D);
    assignment_loss_finalize<<<1, 1, 0, stream>>>(acc, out, 1.0f / (float)B);
}